// Round 10
// baseline (204.324 us; speedup 1.0000x reference)
//
#include <hip/hip_runtime.h>
#include <hip/hip_bf16.h>

// Problem constants (set_attention): B=4, Nq=Nk=2048, D_IN=512, H=8, HS=64
#define BB   4
#define NQ   2048
#define NKK  2048
#define DIN  512
#define NH   8
#define HS   64
#define HD   512  // NH*HS

typedef __hip_bfloat16 bf16;
typedef unsigned short ushort_t;
typedef __attribute__((ext_vector_type(8))) short short8;   // 8 bf16 (4 VGPRs)
typedef __attribute__((ext_vector_type(4))) float f32x4;    // MFMA 16x16 C/D
typedef __attribute__((ext_vector_type(16))) float f32x16;  // MFMA 32x32 C/D
typedef __attribute__((ext_vector_type(4))) unsigned u32x4;

__device__ __forceinline__ unsigned short f2bu(float x) {
  bf16 h = __float2bfloat16(x);
  return *(unsigned short*)&h;
}

// ---------------------------------------------------------------------------
// Kernel 0: weight transpose + bf16 convert.
// z<3:  W[512k][512n] f32 -> Wt_z[n][k] bf16   (64x64 tiles via LDS)
// z==3: Wh[512k][64n] f32 -> Wht[n][k] bf16
// ---------------------------------------------------------------------------
__global__ __launch_bounds__(256) void wtrans_kernel(
    const float* __restrict__ Wq, const float* __restrict__ Wk,
    const float* __restrict__ Wv, const float* __restrict__ Wh,
    ushort_t* __restrict__ Wt, ushort_t* __restrict__ Wht) {
  const int z = blockIdx.z;
  const float* src;
  ushort_t* dst;
  int S;  // source row length (n-dim)
  if (z < 3) {
    src = (z == 0) ? Wq : (z == 1) ? Wk : Wv;
    dst = Wt + (size_t)z * 512 * 512;
    S = 512;
  } else {
    if (blockIdx.y != 0) return;
    src = Wh;
    dst = Wht;
    S = 64;
  }
  const int k0 = blockIdx.x * 64;
  const int n0 = (z < 3) ? blockIdx.y * 64 : 0;

  __shared__ ushort_t Ls[64 * 72];
  const int tid = threadIdx.x;
  {
    int r = tid >> 2, cb = (tid & 3) * 16;
    const float* sp = src + (size_t)(k0 + r) * S + n0 + cb;
#pragma unroll
    for (int ii = 0; ii < 4; ++ii) {
      float4 f = *(const float4*)(sp + ii * 4);
      __align__(8) ushort_t t4[4] = {f2bu(f.x), f2bu(f.y), f2bu(f.z), f2bu(f.w)};
      *(uint2*)(&Ls[r * 72 + cb + ii * 4]) = *(uint2*)t4;
    }
  }
  __syncthreads();
  {
    int rr = tid >> 2, tb = (tid & 3) * 16;
    __align__(16) ushort_t tmp[16];
#pragma unroll
    for (int j = 0; j < 16; ++j) tmp[j] = Ls[(tb + j) * 72 + rr];
    ushort_t* dp = dst + (size_t)(n0 + rr) * 512 + k0 + tb;
    *(int4*)dp       = ((int4*)tmp)[0];
    *(int4*)(dp + 8) = ((int4*)tmp)[1];
  }
}

// ---------------------------------------------------------------------------
// Kernel 1: QKV projections, v2 — X staged ONCE, barrier-free K-loop.
//  - Grid (128, 3): z = 0:q->Qf, 1:k->Kf, 2:k->Vt(transposed). 64 rows/block.
//  - Stage X rows f32->bf16 into LDS once (66.5 KB, +8 pad -> benign banks),
//    ONE barrier; then each wave computes 64x128 (acc[4][8]) with
//    B fragments read DIRECTLY from the L2-resident Wt panel (512 KB shared
//    by 128 blocks). No per-K-step barriers, no B LDS round-trip, X read
//    once per block (was 4x).
//  - Q scaled by (1/sqrt(64))*log2(e) so attention uses exp2 directly.
//  - z==2 writes V transposed: Vt[(b*512+col)*2048 + t] via aligned uint2.
// ---------------------------------------------------------------------------
__global__ __launch_bounds__(256) void proj_kernel(
    const float* __restrict__ q, const float* __restrict__ k,
    const ushort_t* __restrict__ Wt, ushort_t* __restrict__ Qf,
    ushort_t* __restrict__ Kf, ushort_t* __restrict__ Vt) {
  const int z = blockIdx.y;                 // 0:q->Qf 1:k->Kf 2:k->Vt
  const float* X = (z == 0) ? q : k;
  const ushort_t* Wz = Wt + (size_t)z * 512 * 512;
  const float sc = (z == 0) ? 0.18033688011112042f : 1.0f;

  __shared__ ushort_t Xs[64 * 520];         // [row][k] bf16, row pad +8

  const int tid  = threadIdx.x;
  const int lane = tid & 63;
  const int w    = tid >> 6;                // wave -> n-chunk w*128
  const int quad = lane >> 4;
  const int c    = lane & 15;

  const int m0 = blockIdx.x * 64;

  // ---- stage X once: 4 threads/row, f32 -> bf16 ----
  {
    const int r  = tid >> 2;
    const int c4 = (tid & 3) * 4;           // float4 base col, step 16
    const float* xp = X + (size_t)(m0 + r) * DIN;
    ushort_t* lp = &Xs[r * 520];
#pragma unroll
    for (int i = 0; i < 32; ++i) {
      const int col = c4 + i * 16;
      float4 f = *(const float4*)(xp + col);
      __align__(8) ushort_t t4[4] = {f2bu(f.x), f2bu(f.y), f2bu(f.z), f2bu(f.w)};
      *(uint2*)(lp + col) = *(uint2*)t4;
    }
  }
  __syncthreads();

  const int n0w = w * 128;

  f32x4 acc[4][8];
#pragma unroll
  for (int m = 0; m < 4; ++m)
#pragma unroll
    for (int n = 0; n < 8; ++n) acc[m][n] = (f32x4)0.0f;

#pragma unroll 2
  for (int ks = 0; ks < 16; ++ks) {
    short8 af[4];
#pragma unroll
    for (int m = 0; m < 4; ++m)
      af[m] = *(const short8*)(&Xs[(m * 16 + c) * 520 + ks * 32 + quad * 8]);
#pragma unroll
    for (int n = 0; n < 8; ++n) {
      short8 bn = *(const short8*)(Wz + (size_t)(n0w + n * 16 + c) * 512 +
                                   ks * 32 + quad * 8);
#pragma unroll
      for (int m = 0; m < 4; ++m)
        acc[m][n] = __builtin_amdgcn_mfma_f32_16x16x32_bf16(af[m], bn, acc[m][n], 0, 0, 0);
    }
  }

  if (z == 2) {
    // V: transposed write; 4 consecutive tokens per lane -> aligned uint2.
#pragma unroll
    for (int m = 0; m < 4; ++m)
#pragma unroll
      for (int n = 0; n < 8; ++n) {
        const int row0 = m0 + m * 16 + quad * 4;   // token base (mult of 4)
        const int col  = n0w + n * 16 + c;
        const int bb   = row0 >> 11;
        const int t0   = row0 & 2047;
        __align__(8) ushort_t t4[4] = {f2bu(acc[m][n][0]), f2bu(acc[m][n][1]),
                                       f2bu(acc[m][n][2]), f2bu(acc[m][n][3])};
        *(uint2*)(&Vt[((size_t)bb * HD + col) * NKK + t0]) = *(uint2*)t4;
      }
  } else {
    ushort_t* Y = (z == 0) ? Qf : Kf;
#pragma unroll
    for (int m = 0; m < 4; ++m)
#pragma unroll
      for (int n = 0; n < 8; ++n)
#pragma unroll
        for (int r = 0; r < 4; ++r) {
          const int row = m0 + m * 16 + quad * 4 + r;
          const int col = n0w + n * 16 + c;
          Y[(size_t)row * HD + col] = f2bu(acc[m][n][r] * sc);
        }
  }
}

// ---------------------------------------------------------------------------
// Kernel 2: MFMA flash attention, v10 (best measured: 59.1 us).
//  - 64 threads/block, grid 1024 (XCD-swizzled): 1-wave blocks, private
//    32 KB K/V double buffer, zero barriers, no setprio.
//  - Counted vmcnt(16): next tile's 16 global_load_lds stay in flight.
//  - All 16 K/V ds_read_b128 issued back-to-back at tile start.
//  - Each K/V fragment feeds 2 MFMAs (two 32-row q-subtiles).
//  - exp2 softmax (log2e folded into Q scale); T12 cvt_pk+permlane repack.
//  - XOR-swizzled LDS (slot ^ (row&7)) with pre-swizzled global source.
// ---------------------------------------------------------------------------
__global__ __launch_bounds__(64, 1) void attn_kernel(
    const ushort_t* __restrict__ Qf, const ushort_t* __restrict__ Kf,
    const ushort_t* __restrict__ Vt, ushort_t* __restrict__ CTX) {
  // XCD-aware decode: 1024 blocks, xcd = id & 7 (round-robin heuristic).
  const int id   = blockIdx.x;
  const int xcd  = id & 7;
  const int slot = id >> 3;                // 0..127 within xcd
  const int p    = xcd * 4 + (slot >> 5);  // panel 0..31
  const int qb   = slot & 31;              // q-block 0..31 (64 rows each)
  const int h    = p & 7;
  const int b    = p >> 3;

  __shared__ ushort_t Kt[2][4096];  // [buf][key][d] 16B slots, swizzled
  __shared__ ushort_t Vs[2][4096];  // [buf][d][key] 16B slots, swizzled

  const int lane = threadIdx.x & 63;
  const int ql   = lane & 31;     // q (and A-row / B-col) index
  const int hi   = lane >> 5;     // lane half

  const int q0 = qb * 64;  // wave owns q0 .. q0+63

  // Q as B operand: bq[qs][ks] = Q[q0+qs*32+ql][ks*16 + hi*8 .. +7]
  short8 bq[2][4];
#pragma unroll
  for (int qs = 0; qs < 2; ++qs) {
    const ushort_t* qp =
        Qf + (size_t)(b * NQ + q0 + qs * 32 + ql) * HD + h * HS + hi * 8;
#pragma unroll
    for (int ks = 0; ks < 4; ++ks) bq[qs][ks] = *(const short8*)(qp + ks * 16);
  }

  // Staging: single wave stages the full 64x64 tile (16 global_load_lds).
  const int sub  = lane >> 3;      // row within 8-row chunk == row & 7
  const int slt  = lane & 7;       // 16B slot within row
  const int csrc = slt ^ sub;      // pre-swizzled source column (16B units)
  const ushort_t* kp0 =
      Kf + (size_t)(b * NKK + sub) * HD + h * HS + csrc * 8;
  const ushort_t* vp0 =
      Vt + (size_t)((b * NH + h) * HS + sub) * NKK + csrc * 8;

  auto stage = [&](int buf, int kt) {
    const ushort_t* kp = kp0 + (size_t)kt * 64 * HD;
    const ushort_t* vp = vp0 + (size_t)kt * 64;
#pragma unroll
    for (int i = 0; i < 8; ++i) {
      __builtin_amdgcn_global_load_lds(
          (const __attribute__((address_space(1))) unsigned*)(kp + (size_t)i * 8 * HD),
          (__attribute__((address_space(3))) unsigned*)(&Kt[buf][i * 512]),
          16, 0, 0);
      __builtin_amdgcn_global_load_lds(
          (const __attribute__((address_space(1))) unsigned*)(vp + (size_t)i * 8 * NKK),
          (__attribute__((address_space(3))) unsigned*)(&Vs[buf][i * 512]),
          16, 0, 0);
    }
  };

  f32x16 o[2][2];  // [qs][ng]
#pragma unroll
  for (int qs = 0; qs < 2; ++qs)
#pragma unroll
    for (int ng = 0; ng < 2; ++ng) o[qs][ng] = (f32x16)0.0f;
  float lsum[2] = {0.0f, 0.0f};

  stage(0, 0);

  for (int t = 0; t < NKK / 64; ++t) {
    const int buf = t & 1;
    if (t < NKK / 64 - 1) {
      stage(buf ^ 1, t + 1);
      // prev tile's 16 loads done; the 16 just issued stay in flight
      asm volatile("s_waitcnt vmcnt(16)" ::: "memory");
    } else {
      asm volatile("s_waitcnt vmcnt(0)" ::: "memory");
    }
    const ushort_t* kb = &Kt[buf][0];
    const ushort_t* vb = &Vs[buf][0];

    // Prefetch ALL fragments for this tile: 16 back-to-back ds_read_b128.
    short8 ak[2][4], bv[2][4];
#pragma unroll
    for (int kg = 0; kg < 2; ++kg) {
      const int krow = kg * 32 + ql;
#pragma unroll
      for (int ks = 0; ks < 4; ++ks)
        ak[kg][ks] = *(const short8*)(&kb[krow * 64 + (((ks * 2 + hi) ^ (krow & 7)) * 8)]);
    }
#pragma unroll
    for (int ng = 0; ng < 2; ++ng) {
      const int vrow = ng * 32 + ql;
#pragma unroll
      for (int ks = 0; ks < 4; ++ks)
        bv[ng][ks] = *(const short8*)(&vb[vrow * 64 + (((ks * 2 + hi) ^ (vrow & 7)) * 8)]);
    }

#pragma unroll
    for (int kg = 0; kg < 2; ++kg) {
      // S^T = K @ Q^T for both q-subtiles, sharing each K fragment.
      f32x16 s[2];
      s[0] = (f32x16)0.0f;
      s[1] = (f32x16)0.0f;
#pragma unroll
      for (int ks = 0; ks < 4; ++ks) {
        s[0] = __builtin_amdgcn_mfma_f32_32x32x16_bf16(ak[kg][ks], bq[0][ks], s[0], 0, 0, 0);
        s[1] = __builtin_amdgcn_mfma_f32_32x32x16_bf16(ak[kg][ks], bq[1][ks], s[1], 0, 0, 0);
      }

      // Softmax (no-max, exp2) + in-register repack to PV A-fragments.
      short8 pa[2][2];  // [qs][sp]
#pragma unroll
      for (int qs = 0; qs < 2; ++qs) {
        float p_[16];
#pragma unroll
        for (int r = 0; r < 16; ++r) p_[r] = __builtin_amdgcn_exp2f(s[qs][r]);
        {
          float a0 = p_[0] + p_[1], a1 = p_[2] + p_[3], a2 = p_[4] + p_[5], a3 = p_[6] + p_[7];
          float a4 = p_[8] + p_[9], a5 = p_[10] + p_[11], a6 = p_[12] + p_[13], a7 = p_[14] + p_[15];
          a0 += a1; a2 += a3; a4 += a5; a6 += a7;
          lsum[qs] += (a0 + a2) + (a4 + a6);
        }
#pragma unroll
        for (int sp = 0; sp < 2; ++sp) {
          unsigned wA, wB, wC, wD;
          asm("v_cvt_pk_bf16_f32 %0, %1, %2" : "=v"(wA) : "v"(p_[8 * sp + 0]), "v"(p_[8 * sp + 1]));
          asm("v_cvt_pk_bf16_f32 %0, %1, %2" : "=v"(wB) : "v"(p_[8 * sp + 2]), "v"(p_[8 * sp + 3]));
          asm("v_cvt_pk_bf16_f32 %0, %1, %2" : "=v"(wC) : "v"(p_[8 * sp + 4]), "v"(p_[8 * sp + 5]));
          asm("v_cvt_pk_bf16_f32 %0, %1, %2" : "=v"(wD) : "v"(p_[8 * sp + 6]), "v"(p_[8 * sp + 7]));
          asm("v_permlane32_swap_b32 %0, %1" : "+v"(wA), "+v"(wC));
          asm("v_permlane32_swap_b32 %0, %1" : "+v"(wB), "+v"(wD));
          u32x4 pw;
          pw.x = wA;  // j0,j1
          pw.y = wB;  // j2,j3
          pw.z = wC;  // j4,j5
          pw.w = wD;  // j6,j7
          pa[qs][sp] = __builtin_bit_cast(short8, pw);
        }
      }

      // O += P @ V : each V fragment feeds both q-subtiles.
#pragma unroll
      for (int sp = 0; sp < 2; ++sp) {
        const int ks = kg * 2 + sp;
#pragma unroll
        for (int ng = 0; ng < 2; ++ng) {
          o[0][ng] = __builtin_amdgcn_mfma_f32_32x32x16_bf16(pa[0][sp], bv[ng][ks], o[0][ng], 0, 0, 0);
          o[1][ng] = __builtin_amdgcn_mfma_f32_32x32x16_bf16(pa[1][sp], bv[ng][ks], o[1][ng], 0, 0, 0);
        }
      }
    }
  }

  // Denominator: lane + lane^32 cover all 2048 keys of column q.
  float inv[2];
#pragma unroll
  for (int qs = 0; qs < 2; ++qs) {
    float tot = lsum[qs] + __shfl_xor(lsum[qs], 32);
    inv[qs] = 1.0f / tot;
  }

  // O layout: row q = (reg&3)+8*(reg>>2)+4*hi, col d = ng*32 + ql.
#pragma unroll
  for (int qs = 0; qs < 2; ++qs)
#pragma unroll
    for (int r = 0; r < 16; ++r) {
      int qr = (r & 3) + 8 * (r >> 2) + 4 * hi;
      float iv = __shfl(inv[qs], qr);
      size_t base = (size_t)(b * NQ + q0 + qs * 32 + qr) * HD + h * HS + ql;
      CTX[base]      = f2bu(o[qs][0][r] * iv);
      CTX[base + 32] = f2bu(o[qs][1][r] * iv);
    }
}

// ---------------------------------------------------------------------------
// Kernel 3: out[8192,64] = CTX[8192,512] @ Wh[512,64], LDS-free MFMA.
// ---------------------------------------------------------------------------
__global__ __launch_bounds__(64) void outproj_kernel(
    const ushort_t* __restrict__ CTX, const ushort_t* __restrict__ Wht,
    float* __restrict__ out) {
  const int lane = threadIdx.x & 63;
  const int quad = lane >> 4, c = lane & 15;
  const int m0 = blockIdx.x * 16;

  f32x4 o[4];
#pragma unroll
  for (int n = 0; n < 4; ++n) o[n] = (f32x4)0.0f;

  const ushort_t* arow = CTX + (size_t)(m0 + c) * HD;
#pragma unroll 4
  for (int ks = 0; ks < 16; ++ks) {
    short8 a = *(const short8*)(arow + ks * 32 + quad * 8);
#pragma unroll
    for (int nd = 0; nd < 4; ++nd) {
      short8 bn = *(const short8*)(Wht + (size_t)(nd * 16 + c) * 512 + ks * 32 + quad * 8);
      o[nd] = __builtin_amdgcn_mfma_f32_16x16x32_bf16(a, bn, o[nd], 0, 0, 0);
    }
  }
#pragma unroll
  for (int nd = 0; nd < 4; ++nd)
#pragma unroll
    for (int r = 0; r < 4; ++r)
      out[(size_t)(m0 + quad * 4 + r) * HS + nd * 16 + c] = o[nd][r];
}

// ---------------------------------------------------------------------------
extern "C" void kernel_launch(void* const* d_in, const int* in_sizes, int n_in,
                              void* d_out, int out_size, void* d_ws,
                              size_t ws_size, hipStream_t stream) {
  const float* q  = (const float*)d_in[0];
  const float* k  = (const float*)d_in[1];
  const float* Wq = (const float*)d_in[2];
  const float* Wk = (const float*)d_in[3];
  const float* Wv = (const float*)d_in[4];
  const float* Wh = (const float*)d_in[5];
  float* out = (float*)d_out;

  // Workspace (bf16/ushort): Qf|Kf|Vt|CTX|(unused) + Wt (1.5 MiB) + Wht
  const size_t E = (size_t)BB * NQ * HD;
  ushort_t* ws  = (ushort_t*)d_ws;
  ushort_t* Qf  = ws;
  ushort_t* Kf  = Qf + E;
  ushort_t* Vt  = Kf + E;
  ushort_t* CTX = Vt + E;
  ushort_t* Vf  = CTX + E;                     // unused (kept for layout)
  ushort_t* Wt  = Vf + E;                      // 3 x 512 x 512
  ushort_t* Wht = Wt + (size_t)3 * 512 * 512;  // 64 x 512

  wtrans_kernel<<<dim3(8, 8, 4), 256, 0, stream>>>(Wq, Wk, Wv, Wh, Wt, Wht);
  proj_kernel<<<dim3(BB * NQ / 64, 3), 256, 0, stream>>>(
      q, k, Wt, Qf, Kf, Vt);
  attn_kernel<<<dim3(32 * NH * BB), 64, 0, stream>>>(Qf, Kf, Vt, CTX);
  outproj_kernel<<<dim3(BB * NQ / 16), 64, 0, stream>>>(CTX, Wht, out);
}

// Round 11
// 166.929 us; speedup vs baseline: 1.2240x; 1.2240x over previous
//
#include <hip/hip_runtime.h>
#include <hip/hip_bf16.h>

// Problem constants (set_attention): B=4, Nq=Nk=2048, D_IN=512, H=8, HS=64
#define BB   4
#define NQ   2048
#define NKK  2048
#define DIN  512
#define NH   8
#define HS   64
#define HD   512  // NH*HS

typedef __hip_bfloat16 bf16;
typedef unsigned short ushort_t;
typedef __attribute__((ext_vector_type(8))) short short8;   // 8 bf16 (4 VGPRs)
typedef __attribute__((ext_vector_type(4))) float f32x4;    // MFMA 16x16 C/D
typedef __attribute__((ext_vector_type(16))) float f32x16;  // MFMA 32x32 C/D
typedef __attribute__((ext_vector_type(4))) unsigned u32x4;

__device__ __forceinline__ unsigned short f2bu(float x) {
  bf16 h = __float2bfloat16(x);
  return *(unsigned short*)&h;
}

// ---------------------------------------------------------------------------
// Kernel 0: weight prep.
// z<3: W[512k][512n] f32 -> FRAGMENT-LINEAR bf16 layout:
//      Wt[((z*4+nc)*16+ks)*4096 + (n*64+lane)*8 + j] =
//        W[ks*32 + (lane>>4)*8 + j][nc*128 + n*16 + (lane&15)]
//      so proj's B-fragment read is ONE coalesced 1KB wave transaction.
// z==3: Wh[512k][64n] f32 -> Wht[n][k] bf16 (row-major, for outproj).
// ---------------------------------------------------------------------------
__global__ __launch_bounds__(256) void wtrans_kernel(
    const float* __restrict__ Wq, const float* __restrict__ Wk,
    const float* __restrict__ Wv, const float* __restrict__ Wh,
    ushort_t* __restrict__ Wt, ushort_t* __restrict__ Wht) {
  __shared__ ushort_t Ls[4608];
  const int tid = threadIdx.x;
  const int z = blockIdx.z;

  if (z == 3) {  // Wh -> Wht[n][k], old 64x64 transpose path
    if (blockIdx.y != 0 || blockIdx.x >= 8) return;
    const int k0 = blockIdx.x * 64;
    {
      int r = tid >> 2, cb = (tid & 3) * 16;
      const float* sp = Wh + (size_t)(k0 + r) * 64 + cb;
#pragma unroll
      for (int ii = 0; ii < 4; ++ii) {
        float4 f = *(const float4*)(sp + ii * 4);
        __align__(8) ushort_t t4[4] = {f2bu(f.x), f2bu(f.y), f2bu(f.z), f2bu(f.w)};
        *(uint2*)(&Ls[r * 72 + cb + ii * 4]) = *(uint2*)t4;
      }
    }
    __syncthreads();
    {
      int rr = tid >> 2, tb = (tid & 3) * 16;
      __align__(16) ushort_t tmp[16];
#pragma unroll
      for (int j = 0; j < 16; ++j) tmp[j] = Ls[(tb + j) * 72 + rr];
      ushort_t* dp = Wht + (size_t)rr * 512 + k0 + tb;
      *(int4*)dp       = ((int4*)tmp)[0];
      *(int4*)(dp + 8) = ((int4*)tmp)[1];
    }
    return;
  }

  // z<3: fragment-linear. Block = one (z, nc, ks): 32 k-rows x 128 n-cols.
  const int ks = blockIdx.x;   // 0..15
  const int nc = blockIdx.y;   // 0..3
  const float* src = (z == 0) ? Wq : (z == 1) ? Wk : Wv;
  {
    int kk = tid >> 3;              // 0..31
    int c0 = (tid & 7) * 16;        // 0..112
    const float* sp = src + (size_t)(ks * 32 + kk) * 512 + nc * 128 + c0;
#pragma unroll
    for (int ii = 0; ii < 4; ++ii) {
      float4 f = *(const float4*)(sp + ii * 4);
      __align__(8) ushort_t t4[4] = {f2bu(f.x), f2bu(f.y), f2bu(f.z), f2bu(f.w)};
      *(uint2*)(&Ls[kk * 136 + c0 + ii * 4]) = *(uint2*)t4;
    }
  }
  __syncthreads();
  {
    ushort_t* dst = Wt + (((size_t)z * 4 + nc) * 16 + ks) * 4096;
#pragma unroll
    for (int f2 = 0; f2 < 2; ++f2) {
      const int f  = tid * 2 + f2;   // fragment id 0..511
      const int n  = f >> 6;
      const int lo = f & 63;
      const int cc = lo & 15, qq = lo >> 4;
      __align__(16) ushort_t tmp[8];
#pragma unroll
      for (int j = 0; j < 8; ++j) tmp[j] = Ls[(qq * 8 + j) * 136 + n * 16 + cc];
      *(int4*)(dst + f * 8) = *(int4*)tmp;
    }
  }
}

// ---------------------------------------------------------------------------
// Kernel 1: QKV projections, v3 — X staged once, COALESCED fragment-linear
// B reads, 32-row blocks for occupancy.
//  - Grid (256, 3): z = 0:q->Qf, 1:k->Kf, 2:k->Vt(transposed). 32 rows/blk,
//    Xs = 33.5 KB -> 3 blocks/CU resident (12 waves/CU, 3/SIMD).
//  - Stage X f32->bf16 once, ONE barrier; each wave computes 32x128 via
//    acc[2][8]; B fragment = one coalesced 1KB read from the L2-resident
//    fragment-linear Wt (fixes round-10's 16-way scattered B reads).
//  - Q scaled by (1/sqrt(64))*log2(e); z==2 writes V transposed (uint2).
// ---------------------------------------------------------------------------
__global__ __launch_bounds__(256) void proj_kernel(
    const float* __restrict__ q, const float* __restrict__ k,
    const ushort_t* __restrict__ Wt, ushort_t* __restrict__ Qf,
    ushort_t* __restrict__ Kf, ushort_t* __restrict__ Vt) {
  const int z = blockIdx.y;                 // 0:q->Qf 1:k->Kf 2:k->Vt
  const float* X = (z == 0) ? q : k;
  const float sc = (z == 0) ? 0.18033688011112042f : 1.0f;

  __shared__ ushort_t Xs[32 * 524];         // [row][k] bf16, stride 524

  const int tid  = threadIdx.x;
  const int lane = tid & 63;
  const int w    = tid >> 6;                // wave -> n-chunk w*128
  const int quad = lane >> 4;
  const int c    = lane & 15;

  const int m0 = blockIdx.x * 32;

  // ---- stage X once: 8 threads/row ----
  {
    const int r  = tid >> 3;                // 0..31
    const int c0 = (tid & 7) * 4;
    const float* xp = X + (size_t)(m0 + r) * DIN;
    ushort_t* lp = &Xs[r * 524];
#pragma unroll
    for (int i = 0; i < 16; ++i) {
      const int col = c0 + i * 32;
      float4 f = *(const float4*)(xp + col);
      __align__(8) ushort_t t4[4] = {f2bu(f.x), f2bu(f.y), f2bu(f.z), f2bu(f.w)};
      *(uint2*)(lp + col) = *(uint2*)t4;
    }
  }
  __syncthreads();

  const ushort_t* Wz = Wt + (((size_t)z * 4 + w) * 16) * 4096 + lane * 8;

  f32x4 acc[2][8];
#pragma unroll
  for (int m = 0; m < 2; ++m)
#pragma unroll
    for (int n = 0; n < 8; ++n) acc[m][n] = (f32x4)0.0f;

#pragma unroll 4
  for (int ks = 0; ks < 16; ++ks) {
    short8 af0 = *(const short8*)(&Xs[c * 524 + ks * 32 + quad * 8]);
    short8 af1 = *(const short8*)(&Xs[(16 + c) * 524 + ks * 32 + quad * 8]);
    const ushort_t* wk = Wz + (size_t)ks * 4096;
#pragma unroll
    for (int n = 0; n < 8; ++n) {
      short8 bn = *(const short8*)(wk + n * 512);   // coalesced 1KB/wave
      acc[0][n] = __builtin_amdgcn_mfma_f32_16x16x32_bf16(af0, bn, acc[0][n], 0, 0, 0);
      acc[1][n] = __builtin_amdgcn_mfma_f32_16x16x32_bf16(af1, bn, acc[1][n], 0, 0, 0);
    }
  }

  if (z == 2) {
    // V: transposed write; 4 consecutive tokens per lane -> aligned uint2.
#pragma unroll
    for (int m = 0; m < 2; ++m)
#pragma unroll
      for (int n = 0; n < 8; ++n) {
        const int row0 = m0 + m * 16 + quad * 4;   // token base (mult of 4)
        const int col  = w * 128 + n * 16 + c;
        const int bb   = row0 >> 11;
        const int t0   = row0 & 2047;
        __align__(8) ushort_t t4[4] = {f2bu(acc[m][n][0]), f2bu(acc[m][n][1]),
                                       f2bu(acc[m][n][2]), f2bu(acc[m][n][3])};
        *(uint2*)(&Vt[((size_t)bb * HD + col) * NKK + t0]) = *(uint2*)t4;
      }
  } else {
    ushort_t* Y = (z == 0) ? Qf : Kf;
#pragma unroll
    for (int m = 0; m < 2; ++m)
#pragma unroll
      for (int n = 0; n < 8; ++n)
#pragma unroll
        for (int r = 0; r < 4; ++r) {
          const int row = m0 + m * 16 + quad * 4 + r;
          const int col = w * 128 + n * 16 + c;
          Y[(size_t)row * HD + col] = f2bu(acc[m][n][r] * sc);
        }
  }
}

// ---------------------------------------------------------------------------
// Kernel 2: MFMA flash attention, v10 (best measured: 59.1 us). Unchanged.
//  - 64 threads/block, grid 1024 (XCD-swizzled): 1-wave blocks, private
//    32 KB K/V double buffer, zero barriers, no setprio.
//  - Counted vmcnt(16); 16 back-to-back ds_read_b128 per tile.
//  - exp2 softmax (log2e folded into Q scale); T12 cvt_pk+permlane repack.
//  - XOR-swizzled LDS (slot ^ (row&7)) with pre-swizzled global source.
// ---------------------------------------------------------------------------
__global__ __launch_bounds__(64, 1) void attn_kernel(
    const ushort_t* __restrict__ Qf, const ushort_t* __restrict__ Kf,
    const ushort_t* __restrict__ Vt, ushort_t* __restrict__ CTX) {
  const int id   = blockIdx.x;
  const int xcd  = id & 7;
  const int slot = id >> 3;                // 0..127 within xcd
  const int p    = xcd * 4 + (slot >> 5);  // panel 0..31
  const int qb   = slot & 31;              // q-block 0..31 (64 rows each)
  const int h    = p & 7;
  const int b    = p >> 3;

  __shared__ ushort_t Kt[2][4096];  // [buf][key][d] 16B slots, swizzled
  __shared__ ushort_t Vs[2][4096];  // [buf][d][key] 16B slots, swizzled

  const int lane = threadIdx.x & 63;
  const int ql   = lane & 31;     // q (and A-row / B-col) index
  const int hi   = lane >> 5;     // lane half

  const int q0 = qb * 64;  // wave owns q0 .. q0+63

  // Q as B operand: bq[qs][ks] = Q[q0+qs*32+ql][ks*16 + hi*8 .. +7]
  short8 bq[2][4];
#pragma unroll
  for (int qs = 0; qs < 2; ++qs) {
    const ushort_t* qp =
        Qf + (size_t)(b * NQ + q0 + qs * 32 + ql) * HD + h * HS + hi * 8;
#pragma unroll
    for (int ks = 0; ks < 4; ++ks) bq[qs][ks] = *(const short8*)(qp + ks * 16);
  }

  // Staging: single wave stages the full 64x64 tile (16 global_load_lds).
  const int sub  = lane >> 3;      // row within 8-row chunk == row & 7
  const int slt  = lane & 7;       // 16B slot within row
  const int csrc = slt ^ sub;      // pre-swizzled source column (16B units)
  const ushort_t* kp0 =
      Kf + (size_t)(b * NKK + sub) * HD + h * HS + csrc * 8;
  const ushort_t* vp0 =
      Vt + (size_t)((b * NH + h) * HS + sub) * NKK + csrc * 8;

  auto stage = [&](int buf, int kt) {
    const ushort_t* kp = kp0 + (size_t)kt * 64 * HD;
    const ushort_t* vp = vp0 + (size_t)kt * 64;
#pragma unroll
    for (int i = 0; i < 8; ++i) {
      __builtin_amdgcn_global_load_lds(
          (const __attribute__((address_space(1))) unsigned*)(kp + (size_t)i * 8 * HD),
          (__attribute__((address_space(3))) unsigned*)(&Kt[buf][i * 512]),
          16, 0, 0);
      __builtin_amdgcn_global_load_lds(
          (const __attribute__((address_space(1))) unsigned*)(vp + (size_t)i * 8 * NKK),
          (__attribute__((address_space(3))) unsigned*)(&Vs[buf][i * 512]),
          16, 0, 0);
    }
  };

  f32x16 o[2][2];  // [qs][ng]
#pragma unroll
  for (int qs = 0; qs < 2; ++qs)
#pragma unroll
    for (int ng = 0; ng < 2; ++ng) o[qs][ng] = (f32x16)0.0f;
  float lsum[2] = {0.0f, 0.0f};

  stage(0, 0);

  for (int t = 0; t < NKK / 64; ++t) {
    const int buf = t & 1;
    if (t < NKK / 64 - 1) {
      stage(buf ^ 1, t + 1);
      // prev tile's 16 loads done; the 16 just issued stay in flight
      asm volatile("s_waitcnt vmcnt(16)" ::: "memory");
    } else {
      asm volatile("s_waitcnt vmcnt(0)" ::: "memory");
    }
    const ushort_t* kb = &Kt[buf][0];
    const ushort_t* vb = &Vs[buf][0];

    // Prefetch ALL fragments for this tile: 16 back-to-back ds_read_b128.
    short8 ak[2][4], bv[2][4];
#pragma unroll
    for (int kg = 0; kg < 2; ++kg) {
      const int krow = kg * 32 + ql;
#pragma unroll
      for (int ks = 0; ks < 4; ++ks)
        ak[kg][ks] = *(const short8*)(&kb[krow * 64 + (((ks * 2 + hi) ^ (krow & 7)) * 8)]);
    }
#pragma unroll
    for (int ng = 0; ng < 2; ++ng) {
      const int vrow = ng * 32 + ql;
#pragma unroll
      for (int ks = 0; ks < 4; ++ks)
        bv[ng][ks] = *(const short8*)(&vb[vrow * 64 + (((ks * 2 + hi) ^ (vrow & 7)) * 8)]);
    }

#pragma unroll
    for (int kg = 0; kg < 2; ++kg) {
      // S^T = K @ Q^T for both q-subtiles, sharing each K fragment.
      f32x16 s[2];
      s[0] = (f32x16)0.0f;
      s[1] = (f32x16)0.0f;
#pragma unroll
      for (int ks = 0; ks < 4; ++ks) {
        s[0] = __builtin_amdgcn_mfma_f32_32x32x16_bf16(ak[kg][ks], bq[0][ks], s[0], 0, 0, 0);
        s[1] = __builtin_amdgcn_mfma_f32_32x32x16_bf16(ak[kg][ks], bq[1][ks], s[1], 0, 0, 0);
      }

      // Softmax (no-max, exp2) + in-register repack to PV A-fragments.
      short8 pa[2][2];  // [qs][sp]
#pragma unroll
      for (int qs = 0; qs < 2; ++qs) {
        float p_[16];
#pragma unroll
        for (int r = 0; r < 16; ++r) p_[r] = __builtin_amdgcn_exp2f(s[qs][r]);
        {
          float a0 = p_[0] + p_[1], a1 = p_[2] + p_[3], a2 = p_[4] + p_[5], a3 = p_[6] + p_[7];
          float a4 = p_[8] + p_[9], a5 = p_[10] + p_[11], a6 = p_[12] + p_[13], a7 = p_[14] + p_[15];
          a0 += a1; a2 += a3; a4 += a5; a6 += a7;
          lsum[qs] += (a0 + a2) + (a4 + a6);
        }
#pragma unroll
        for (int sp = 0; sp < 2; ++sp) {
          unsigned wA, wB, wC, wD;
          asm("v_cvt_pk_bf16_f32 %0, %1, %2" : "=v"(wA) : "v"(p_[8 * sp + 0]), "v"(p_[8 * sp + 1]));
          asm("v_cvt_pk_bf16_f32 %0, %1, %2" : "=v"(wB) : "v"(p_[8 * sp + 2]), "v"(p_[8 * sp + 3]));
          asm("v_cvt_pk_bf16_f32 %0, %1, %2" : "=v"(wC) : "v"(p_[8 * sp + 4]), "v"(p_[8 * sp + 5]));
          asm("v_cvt_pk_bf16_f32 %0, %1, %2" : "=v"(wD) : "v"(p_[8 * sp + 6]), "v"(p_[8 * sp + 7]));
          asm("v_permlane32_swap_b32 %0, %1" : "+v"(wA), "+v"(wC));
          asm("v_permlane32_swap_b32 %0, %1" : "+v"(wB), "+v"(wD));
          u32x4 pw;
          pw.x = wA;  // j0,j1
          pw.y = wB;  // j2,j3
          pw.z = wC;  // j4,j5
          pw.w = wD;  // j6,j7
          pa[qs][sp] = __builtin_bit_cast(short8, pw);
        }
      }

      // O += P @ V : each V fragment feeds both q-subtiles.
#pragma unroll
      for (int sp = 0; sp < 2; ++sp) {
        const int ks = kg * 2 + sp;
#pragma unroll
        for (int ng = 0; ng < 2; ++ng) {
          o[0][ng] = __builtin_amdgcn_mfma_f32_32x32x16_bf16(pa[0][sp], bv[ng][ks], o[0][ng], 0, 0, 0);
          o[1][ng] = __builtin_amdgcn_mfma_f32_32x32x16_bf16(pa[1][sp], bv[ng][ks], o[1][ng], 0, 0, 0);
        }
      }
    }
  }

  // Denominator: lane + lane^32 cover all 2048 keys of column q.
  float inv[2];
#pragma unroll
  for (int qs = 0; qs < 2; ++qs) {
    float tot = lsum[qs] + __shfl_xor(lsum[qs], 32);
    inv[qs] = 1.0f / tot;
  }

  // O layout: row q = (reg&3)+8*(reg>>2)+4*hi, col d = ng*32 + ql.
#pragma unroll
  for (int qs = 0; qs < 2; ++qs)
#pragma unroll
    for (int r = 0; r < 16; ++r) {
      int qr = (r & 3) + 8 * (r >> 2) + 4 * hi;
      float iv = __shfl(inv[qs], qr);
      size_t base = (size_t)(b * NQ + q0 + qs * 32 + qr) * HD + h * HS + ql;
      CTX[base]      = f2bu(o[qs][0][r] * iv);
      CTX[base + 32] = f2bu(o[qs][1][r] * iv);
    }
}

// ---------------------------------------------------------------------------
// Kernel 3: out[8192,64] = CTX[8192,512] @ Wh[512,64], LDS-free MFMA.
// ---------------------------------------------------------------------------
__global__ __launch_bounds__(64) void outproj_kernel(
    const ushort_t* __restrict__ CTX, const ushort_t* __restrict__ Wht,
    float* __restrict__ out) {
  const int lane = threadIdx.x & 63;
  const int quad = lane >> 4, c = lane & 15;
  const int m0 = blockIdx.x * 16;

  f32x4 o[4];
#pragma unroll
  for (int n = 0; n < 4; ++n) o[n] = (f32x4)0.0f;

  const ushort_t* arow = CTX + (size_t)(m0 + c) * HD;
#pragma unroll 4
  for (int ks = 0; ks < 16; ++ks) {
    short8 a = *(const short8*)(arow + ks * 32 + quad * 8);
#pragma unroll
    for (int nd = 0; nd < 4; ++nd) {
      short8 bn = *(const short8*)(Wht + (size_t)(nd * 16 + c) * 512 + ks * 32 + quad * 8);
      o[nd] = __builtin_amdgcn_mfma_f32_16x16x32_bf16(a, bn, o[nd], 0, 0, 0);
    }
  }
#pragma unroll
  for (int nd = 0; nd < 4; ++nd)
#pragma unroll
    for (int r = 0; r < 4; ++r)
      out[(size_t)(m0 + quad * 4 + r) * HS + nd * 16 + c] = o[nd][r];
}

// ---------------------------------------------------------------------------
extern "C" void kernel_launch(void* const* d_in, const int* in_sizes, int n_in,
                              void* d_out, int out_size, void* d_ws,
                              size_t ws_size, hipStream_t stream) {
  const float* q  = (const float*)d_in[0];
  const float* k  = (const float*)d_in[1];
  const float* Wq = (const float*)d_in[2];
  const float* Wk = (const float*)d_in[3];
  const float* Wv = (const float*)d_in[4];
  const float* Wh = (const float*)d_in[5];
  float* out = (float*)d_out;

  // Workspace (bf16/ushort): Qf|Kf|Vt|CTX|(unused) + Wt (1.5 MiB) + Wht
  const size_t E = (size_t)BB * NQ * HD;
  ushort_t* ws  = (ushort_t*)d_ws;
  ushort_t* Qf  = ws;
  ushort_t* Kf  = Qf + E;
  ushort_t* Vt  = Kf + E;
  ushort_t* CTX = Vt + E;
  ushort_t* Vf  = CTX + E;                     // unused (kept for layout)
  ushort_t* Wt  = Vf + E;                      // 3 x 512 x 512 (frag-linear)
  ushort_t* Wht = Wt + (size_t)3 * 512 * 512;  // 64 x 512

  wtrans_kernel<<<dim3(16, 4, 4), 256, 0, stream>>>(Wq, Wk, Wv, Wh, Wt, Wht);
  proj_kernel<<<dim3(BB * NQ / 32, 3), 256, 0, stream>>>(
      q, k, Wt, Qf, Kf, Vt);
  attn_kernel<<<dim3(32 * NH * BB), 64, 0, stream>>>(Qf, Kf, Vt, CTX);
  outproj_kernel<<<dim3(BB * NQ / 16), 64, 0, stream>>>(CTX, Wht, out);
}